// Round 6
// baseline (75.554 us; speedup 1.0000x reference)
//
#include <hip/hip_runtime.h>
#include <hip/hip_fp16.h>

typedef _Float16 f16x8 __attribute__((ext_vector_type(8)));
typedef float f32x4 __attribute__((ext_vector_type(4)));
typedef unsigned int uint32;

#define LDW 136   // row stride in halves (272B: 16B-aligned)
#define TB  32    // tokens per block (8 waves, 512 threads)

// wait only lgkmcnt(0): vmcnt=63, expcnt=7, lgkmcnt=0 -> 0xC07F
#define WAITLGKM() do { __builtin_amdgcn_s_waitcnt(0xC07F); __builtin_amdgcn_sched_barrier(0); } while(0)

union F16x8U { f16x8 v; __half2 h2[4]; uint2 u2[2]; uint4 u4; };

__device__ __forceinline__ uint32 pk2f(float a, float b) {
  __half2 h = __floats2half2_rn(a, b);
  return *reinterpret_cast<uint32*>(&h);
}
__device__ __forceinline__ float bcast(float v, int sl) {
  return __int_as_float(__builtin_amdgcn_readlane(__float_as_int(v), sl));
}
__device__ __forceinline__ float wred_sum(float v) {
  v += __shfl_xor(v, 32); v += __shfl_xor(v, 16); v += __shfl_xor(v, 8);
  v += __shfl_xor(v, 4);  v += __shfl_xor(v, 2);  v += __shfl_xor(v, 1);
  return v;
}
__device__ __forceinline__ f16x8 ldsv8(const __half* p) {
  return *reinterpret_cast<const f16x8*>(p);   // 16B-aligned -> ds_read_b128
}
__device__ __forceinline__ f32x4 mfma16(f16x8 a, f16x8 b, f32x4 c) {
  return __builtin_amdgcn_mfma_f32_16x16x32_f16(a, b, c, 0, 0, 0);
}
// packed C-frag store: C[m=c_out local][n=tok=fr] -> row-major act[tok][c], 1x ds_write_b64
__device__ __forceinline__ void stp(__half* base, int fr, int fq, int nt, f32x4 a) {
  uint2 u; u.x = pk2f(a[0], a[1]); u.y = pk2f(a[2], a[3]);
  *reinterpret_cast<uint2*>(&base[fr * LDW + nt * 16 + fq * 4]) = u;
}

// ---- workspace layout (halves) ----
#define OFF_WQ   0          // wqT  [c_out 128][c_in 128]
#define OFF_WK2  16384      // wk2  [h 4][i 128][d 40] : wkv[i][h*32+d] (d<32, pad 0)
#define OFF_WV   36864      // wvT  [c_out 128][i 128] : wkv[i][128+c]
#define OFF_WMH  53248      // wmhT
#define OFF_W1   69632      // w1T
#define OFF_W2   86016      // w2T
#define WS_HALVES 102400

__global__ void prep_weights(const float* __restrict__ wq, const float* __restrict__ wkv,
                             const float* __restrict__ wmh, const float* __restrict__ w1,
                             const float* __restrict__ w2, __half* __restrict__ ws) {
  int idx = blockIdx.x * 256 + threadIdx.x;
  if (idx >= WS_HALVES) return;
  float v;
  if (idx < OFF_WK2) {
    int t = idx, c = t >> 7, k = t & 127;
    v = wq[k * 128 + c];
  } else if (idx < OFF_WV) {
    int t = idx - OFF_WK2;
    int d = t % 40, row = t / 40;            // row = h*128 + i
    int h = row >> 7, i = row & 127;
    v = (d < 32) ? wkv[i * 256 + h * 32 + d] : 0.f;
  } else if (idx < OFF_WMH) {
    int t = idx - OFF_WV, c = t >> 7, k = t & 127;
    v = wkv[k * 256 + 128 + c];
  } else if (idx < OFF_W1) {
    int t = idx - OFF_WMH, c = t >> 7, k = t & 127;
    v = wmh[k * 128 + c];
  } else if (idx < OFF_W2) {
    int t = idx - OFF_W1, c = t >> 7, k = t & 127;
    v = w1[k * 128 + c];
  } else {
    int t = idx - OFF_W2, c = t >> 7, k = t & 127;
    v = w2[k * 128 + c];
  }
  ws[idx] = __float2half_rn(v);
}

// load W frags (2 c_out-tiles x 4 k-slices), used as MFMA *A* operand
#define LOADB2(GOFF, NT0, NT1, BF) do {                                          \
  _Pragma("unroll")                                                              \
  for (int t_ = 0; t_ < 2; ++t_) {                                               \
    int nt_ = t_ ? (NT1) : (NT0);                                                \
    _Pragma("unroll")                                                            \
    for (int ks_ = 0; ks_ < 4; ++ks_)                                            \
      BF[t_][ks_] = *reinterpret_cast<const f16x8*>(                             \
          wsv + (GOFF) + (nt_*16 + fr)*128 + ks_*32 + fq*8);                     \
  } } while (0)

// two 16x16 tiles: A = weights (BF), B = activation tile (row-major [tok][c])
#define GEMM2(AT, BF, ACC0, ACC1) do {                                           \
  _Pragma("unroll")                                                              \
  for (int ks_ = 0; ks_ < 4; ++ks_) {                                            \
    f16x8 b_ = ldsv8(&(AT)[fr * LDW + ks_ * 32 + fq * 8]);                       \
    ACC0 = mfma16(BF[0][ks_], b_, ACC0);                                         \
    ACC1 = mfma16(BF[1][ks_], b_, ACC1);                                         \
  } } while (0)

__global__ void __launch_bounds__(512, 6) ca_mfma(
    const float* __restrict__ xq, const float* __restrict__ kvin,
    const __half* __restrict__ wsv,
    const float* __restrict__ bmh, const float* __restrict__ b1,
    const float* __restrict__ b2,
    const float* __restrict__ g1, const float* __restrict__ bb1,
    const float* __restrict__ g2, const float* __restrict__ bb2,
    float* __restrict__ outp)
{
  // LDS: 34816 + 17408 = 52224 B -> 3 blocks/CU (24 waves)
  __shared__ __half QWC[128 * LDW];   // qw/ctx rows [h*32 + tok(0..31)]; then Y/RES/H/V (32 rows each)
  __shared__ __half UBUF[8 * 1088];   // Xh(32 rows) -> per-wave kvw[8][LDW] -> Ob(32 rows)

  const int tid = threadIdx.x;
  const int wv = tid >> 6, lane = tid & 63;
  const int wl = wv & 3, tt = wv >> 2;        // c-role / token-tile
  const int fr = lane & 15, fq = lane >> 4;   // MFMA frag row / k-group
  const int tb = blockIdx.x * TB;
  const int ltb = wv * 4;                     // this wave's 4 attention tokens (in block)

  __half* Xh = UBUF;              // rows 0..31 (dead after P1)
  __half* Ob = UBUF;              // rows 0..31 (written P4, kvw dead)
  __half* Yb   = QWC;             // rows 0..31
  __half* RESb = QWC + 32 * LDW;
  __half* Hb   = QWC + 64 * LDW;
  __half* Vb   = QWC + 96 * LDW;

  const f32x4 ZZ = {0.f, 0.f, 0.f, 0.f};

  // ---- entry: prefetch this wave's token-0 kv + P1 W frags (c-tiles 2wl, 2wl+1) ----
  float4 pre[4];
  {
    const float4* kv4 = reinterpret_cast<const float4*>(kvin + (size_t)(tb + ltb) * 1024);
    pre[0] = kv4[2 * lane];       pre[1] = kv4[2 * lane + 1];
    pre[2] = kv4[2 * lane + 128]; pre[3] = kv4[2 * lane + 129];
  }
  f16x8 bf[2][4];
  LOADB2(OFF_WQ, 2 * wl, 2 * wl + 1, bf);

  // ---- Xh (f16, row-major [tok 0..31][c], stride LDW) ----
  {
    int tok = tid >> 4, ko = (tid & 15) * 8;
    const float4* s0 = reinterpret_cast<const float4*>(xq + (size_t)(tb + tok) * 128 + ko);
    float4 a = s0[0], b = s0[1];
    uint4 u; u.x = pk2f(a.x, a.y); u.y = pk2f(a.z, a.w);
    u.z = pk2f(b.x, b.y); u.w = pk2f(b.z, b.w);
    *reinterpret_cast<uint4*>(&Xh[tok * LDW + ko]) = u;
  }
  __syncthreads();  // 1: Xh ready; bf(wq) + kv pre drained

  // ---- P1: q-slice for own head: tiles (2wl, 2wl+1) of token-tile tt ----
  f16x8 aq;   // P2 B-frag, built in-register from P1 C-frags
  {
    f32x4 aA = ZZ, aB = ZZ;
    GEMM2(Xh + tt * 16 * LDW, bf, aA, aB);
    // handoff C-frag(f32) -> P2 B-frag(f16): pack, 8 shuffles, 4 selects.
    // target lane (fr,fq) needs q[tok=fr][c = wl*32 + fq*8+j]:
    //   tile t=fq>>1, src lanes (fr, 2(fq&1)) and (fr, 2(fq&1)+1), word (j>>1)&1
    uint32 w0a = pk2f(aA[0], aA[1]), w1a = pk2f(aA[2], aA[3]);
    uint32 w0b = pk2f(aB[0], aB[1]), w1b = pk2f(aB[2], aB[3]);
    int srcA = fr + 32 * (fq & 1), srcB = srcA + 16;
    uint32 a0A = (uint32)__shfl((int)w0a, srcA), a1A = (uint32)__shfl((int)w1a, srcA);
    uint32 b0A = (uint32)__shfl((int)w0b, srcA), b1A = (uint32)__shfl((int)w1b, srcA);
    uint32 a0B = (uint32)__shfl((int)w0a, srcB), a1B = (uint32)__shfl((int)w1a, srcB);
    uint32 b0B = (uint32)__shfl((int)w0b, srcB), b1B = (uint32)__shfl((int)w1b, srcB);
    bool thi = (fq >> 1) != 0;
    F16x8U bu;
    bu.u4.x = thi ? b0A : a0A;   // j=0,1
    bu.u4.y = thi ? b1A : a1A;   // j=2,3
    bu.u4.z = thi ? b0B : a0B;   // j=4,5
    bu.u4.w = thi ? b1B : a1B;   // j=6,7
    aq = bu.v;
  }

  // ---- P2: qw[wl][tt][i] = wk2[wl](A) @ q(B) -> QWC rows wl*32 + tt*16 + fr ----
  {
    f16x8 bq[8];
#pragma unroll
    for (int nt = 0; nt < 8; ++nt)
      bq[nt] = *reinterpret_cast<const f16x8*>(
          wsv + OFF_WK2 + (wl * 128 + nt * 16 + fr) * 40 + fq * 8);
#pragma unroll
    for (int nt = 0; nt < 8; ++nt) {
      f32x4 acc = mfma16(bq[nt], aq, ZZ);
      uint2 u; u.x = pk2f(acc[0], acc[1]); u.y = pk2f(acc[2], acc[3]);
      *reinterpret_cast<uint2*>(&QWC[(wl * 32 + tt * 16 + fr) * LDW + nt * 16 + fq * 4]) = u;
    }
  }
  __syncthreads();  // 2: qw ready (all heads); Xh reads done (kvw may overwrite)

  // ---- P3: wave-local attention over this wave's 4 tokens ----
  {
    const int p = lane & 31, hh = p >> 3, kk = p & 7, hf = lane >> 5;
    const int kr = lane >> 4, i8 = (lane & 15) * 8;
    const int l2 = 2 * lane;
    __half* kvw = UBUF + wv * 1088;   // [8][LDW] per wave (aliases Xh rows, dead)
#pragma unroll 1
    for (int lt = 0; lt < 4; ++lt) {
      const int gtok = ltb + lt;      // token index within block (0..31)
      WAITLGKM();   // prior iter's ds_reads of kvw done (WAR)
      {
        uint4 u0, u1;
        u0.x = pk2f(pre[0].x, pre[0].y); u0.y = pk2f(pre[0].z, pre[0].w);
        u0.z = pk2f(pre[1].x, pre[1].y); u0.w = pk2f(pre[1].z, pre[1].w);
        u1.x = pk2f(pre[2].x, pre[2].y); u1.y = pk2f(pre[2].z, pre[2].w);
        u1.z = pk2f(pre[3].x, pre[3].y); u1.w = pk2f(pre[3].z, pre[3].w);
        *reinterpret_cast<uint4*>(&kvw[kr * LDW + i8]) = u0;        // rows 0..3
        *reinterpret_cast<uint4*>(&kvw[(4 + kr) * LDW + i8]) = u1;  // rows 4..7
      }
      if (lt < 3) {   // prefetch next token's kv
        const float4* kv4 = reinterpret_cast<const float4*>(kvin + (size_t)(tb + gtok + 1) * 1024);
        pre[0] = kv4[2 * lane];       pre[1] = kv4[2 * lane + 1];
        pre[2] = kv4[2 * lane + 128]; pre[3] = kv4[2 * lane + 129];
      }
      WAITLGKM();   // kv writes visible within wave
      // sim: lane=(hf,hh,kk); dot over 64 i via 8+8 ds_read_b128
      const __half* qrow = &QWC[(hh * 32 + gtok) * LDW + hf * 64];
      const __half* krow = &kvw[kk * LDW + hf * 64];
      __half2 s0 = __floats2half2_rn(0.f, 0.f), s1 = s0;
#pragma unroll
      for (int e = 0; e < 8; ++e) {
        F16x8U q8, k8;
        q8.v = ldsv8(qrow + e * 8);
        k8.v = ldsv8(krow + e * 8);
        s0 = __hfma2(q8.h2[0], k8.h2[0], s0);
        s1 = __hfma2(q8.h2[1], k8.h2[1], s1);
        s0 = __hfma2(q8.h2[2], k8.h2[2], s0);
        s1 = __hfma2(q8.h2[3], k8.h2[3], s1);
      }
      s0 = __hadd2(s0, s1);
      float acc = (__low2float(s0) + __high2float(s0)) * 0.17677669529663687f;
      acc += __shfl_xor(acc, 32);
      float m = acc;
      m = fmaxf(m, __shfl_xor(m, 1));
      m = fmaxf(m, __shfl_xor(m, 2));
      m = fmaxf(m, __shfl_xor(m, 4));
      float e = __expf(acc - m);
      float sden = e;
      sden += __shfl_xor(sden, 1); sden += __shfl_xor(sden, 2); sden += __shfl_xor(sden, 4);
      float at = __fdividef(e, sden);   // lane p holds attn[h=p>>3][k=p&7]
      // ctx[h][c] = sum_k attn*kv ; lane owns cols 2*lane, 2*lane+1
      __half2 kvc[8];
#pragma unroll
      for (int k = 0; k < 8; ++k)
        kvc[k] = *reinterpret_cast<const __half2*>(&kvw[k * LDW + l2]);
#pragma unroll
      for (int h = 0; h < 4; ++h) {
        float c0 = 0.f, c1 = 0.f;
#pragma unroll
        for (int k = 0; k < 8; ++k) {
          float a = bcast(at, h * 8 + k);
          float2 kf = __half22float2(kvc[k]);
          c0 = fmaf(a, kf.x, c0);
          c1 = fmaf(a, kf.y, c1);
        }
        *reinterpret_cast<__half2*>(&QWC[(h * 32 + gtok) * LDW + l2]) =
            __floats2half2_rn(c0, c1);
      }
    }
  }
  LOADB2(OFF_WV, wl, 4 + wl, bf);
  __syncthreads();  // 3: ctx ready; kvw reads done; bf(wv) drained

  // ---- P4: out = WvT(A) @ ctx(B) -> Ob[tok][c]; head-mapped c-tiles (wl, 4+wl) ----
  float2 xr[4];   // residual x for LN1 (lane owns cols 2l,2l+1)
#pragma unroll
  for (int lt = 0; lt < 4; ++lt) {
    int tok = tb + ltb + lt;
    xr[lt] = *reinterpret_cast<const float2*>(&xq[(size_t)tok * 128 + 2 * lane]);
  }
  {
    const int h1 = wl >> 1, h2 = 2 + (wl >> 1);
    f32x4 a1c = ZZ, a2c = ZZ;
#pragma unroll
    for (int ks = 0; ks < 4; ++ks) {
      f16x8 b1f = ldsv8(&QWC[(h1 * 32 + tt * 16 + fr) * LDW + ks * 32 + fq * 8]);
      a1c = mfma16(bf[0][ks], b1f, a1c);
      f16x8 b2f = ldsv8(&QWC[(h2 * 32 + tt * 16 + fr) * LDW + ks * 32 + fq * 8]);
      a2c = mfma16(bf[1][ks], b2f, a2c);
    }
    stp(Ob + tt * 16 * LDW, fr, fq, wl, a1c);
    stp(Ob + tt * 16 * LDW, fr, fq, 4 + wl, a2c);
  }
  LOADB2(OFF_WMH, wl, 4 + wl, bf);
  __syncthreads();  // 4: Ob ready; QWC ctx reads done; bf(wmh) drained

  // ---- P5: y = Wmh(A) @ out(B) -> Yb[tok][c] ----
  {
    f32x4 aA = ZZ, aB = ZZ;
    GEMM2(Ob + tt * 16 * LDW, bf, aA, aB);
    stp(Yb + tt * 16 * LDW, fr, fq, wl, aA);
    stp(Yb + tt * 16 * LDW, fr, fq, 4 + wl, aB);
  }
  LOADB2(OFF_W1, wl, 4 + wl, bf);
  __syncthreads();  // 5: Yb ready; bf(w1) drained

  // ---- LN1 + residual -> RESb (lane owns cols 2l,2l+1) ----
  {
    const int l2 = 2 * lane;
    float2 bm = *reinterpret_cast<const float2*>(&bmh[l2]);
    float2 gg = *reinterpret_cast<const float2*>(&g1[l2]);
    float2 cc = *reinterpret_cast<const float2*>(&bb1[l2]);
#pragma unroll
    for (int lt = 0; lt < 4; ++lt) {
      int row = ltb + lt;
      float2 y = __half22float2(*reinterpret_cast<const __half2*>(&Yb[row * LDW + l2]));
      float v0 = y.x + bm.x, v1 = y.y + bm.y;
      float s = wred_sum(v0 + v1);
      float sq = wred_sum(v0 * v0 + v1 * v1);
      float mu = s * 0.0078125f;
      float var = sq * 0.0078125f - mu * mu;
      float rstd = rsqrtf(var + 1e-5f);
      float r0 = (v0 - mu) * rstd * gg.x + cc.x + xr[lt].x;
      float r1 = (v1 - mu) * rstd * gg.y + cc.y + xr[lt].y;
      *reinterpret_cast<__half2*>(&RESb[row * LDW + l2]) = __floats2half2_rn(r0, r1);
    }
  }
  __syncthreads();  // 6: RESb ready

  // ---- P6: h = gelu(W1(A) @ res(B) + b1) -> Hb[tok][c] ----
  {
    f32x4 aA = ZZ, aB = ZZ;
    GEMM2(RESb + tt * 16 * LDW, bf, aA, aB);
    int c0 = wl * 16 + fq * 4, c1 = 64 + wl * 16 + fq * 4;
    float4 b1a = *reinterpret_cast<const float4*>(&b1[c0]);
    float4 b1b = *reinterpret_cast<const float4*>(&b1[c1]);
    uint2 ua, ub;
    float t0, t1;
    t0 = aA[0] + b1a.x; t0 = 0.5f * t0 * (1.f + erff(t0 * 0.70710678118654752f));
    t1 = aA[1] + b1a.y; t1 = 0.5f * t1 * (1.f + erff(t1 * 0.70710678118654752f));
    ua.x = pk2f(t0, t1);
    t0 = aA[2] + b1a.z; t0 = 0.5f * t0 * (1.f + erff(t0 * 0.70710678118654752f));
    t1 = aA[3] + b1a.w; t1 = 0.5f * t1 * (1.f + erff(t1 * 0.70710678118654752f));
    ua.y = pk2f(t0, t1);
    t0 = aB[0] + b1b.x; t0 = 0.5f * t0 * (1.f + erff(t0 * 0.70710678118654752f));
    t1 = aB[1] + b1b.y; t1 = 0.5f * t1 * (1.f + erff(t1 * 0.70710678118654752f));
    ub.x = pk2f(t0, t1);
    t0 = aB[2] + b1b.z; t0 = 0.5f * t0 * (1.f + erff(t0 * 0.70710678118654752f));
    t1 = aB[3] + b1b.w; t1 = 0.5f * t1 * (1.f + erff(t1 * 0.70710678118654752f));
    ub.y = pk2f(t0, t1);
    *reinterpret_cast<uint2*>(&Hb[(tt * 16 + fr) * LDW + c0]) = ua;
    *reinterpret_cast<uint2*>(&Hb[(tt * 16 + fr) * LDW + c1]) = ub;
  }
  LOADB2(OFF_W2, wl, 4 + wl, bf);
  __syncthreads();  // 7: Hb ready; bf(w2) drained

  // ---- P7: v = W2(A) @ h(B) + b2 + res -> Vb[tok][c] ----
  {
    f32x4 aA = ZZ, aB = ZZ;
    GEMM2(Hb + tt * 16 * LDW, bf, aA, aB);
    int c0 = wl * 16 + fq * 4, c1 = 64 + wl * 16 + fq * 4;
    float4 b2a = *reinterpret_cast<const float4*>(&b2[c0]);
    float4 b2b = *reinterpret_cast<const float4*>(&b2[c1]);
    F16x8U ra, rb;
    ra.u2[0] = *reinterpret_cast<const uint2*>(&RESb[(tt * 16 + fr) * LDW + c0]);
    rb.u2[0] = *reinterpret_cast<const uint2*>(&RESb[(tt * 16 + fr) * LDW + c1]);
    uint2 ua, ub;
    float2 p0 = __half22float2(ra.h2[0]), p1 = __half22float2(ra.h2[1]);
    ua.x = pk2f(aA[0] + b2a.x + p0.x, aA[1] + b2a.y + p0.y);
    ua.y = pk2f(aA[2] + b2a.z + p1.x, aA[3] + b2a.w + p1.y);
    float2 p2 = __half22float2(rb.h2[0]), p3 = __half22float2(rb.h2[1]);
    ub.x = pk2f(aB[0] + b2b.x + p2.x, aB[1] + b2b.y + p2.y);
    ub.y = pk2f(aB[2] + b2b.z + p3.x, aB[3] + b2b.w + p3.y);
    *reinterpret_cast<uint2*>(&Vb[(tt * 16 + fr) * LDW + c0]) = ua;
    *reinterpret_cast<uint2*>(&Vb[(tt * 16 + fr) * LDW + c1]) = ub;
  }
  __syncthreads();  // 8: Vb ready

  // ---- LN2 + store (lane owns cols 2l,2l+1; float2 out) ----
  {
    const int l2 = 2 * lane;
    float2 gg = *reinterpret_cast<const float2*>(&g2[l2]);
    float2 cc = *reinterpret_cast<const float2*>(&bb2[l2]);
#pragma unroll
    for (int lt = 0; lt < 4; ++lt) {
      int row = ltb + lt, tok = tb + row;
      float2 v = __half22float2(*reinterpret_cast<const __half2*>(&Vb[row * LDW + l2]));
      float s = wred_sum(v.x + v.y);
      float sq = wred_sum(v.x * v.x + v.y * v.y);
      float mu = s * 0.0078125f;
      float var = sq * 0.0078125f - mu * mu;
      float rstd = rsqrtf(var + 1e-5f);
      float2 o;
      o.x = (v.x - mu) * rstd * gg.x + cc.x;
      o.y = (v.y - mu) * rstd * gg.y + cc.y;
      *reinterpret_cast<float2*>(&outp[(size_t)tok * 128 + l2]) = o;
    }
  }
}

extern "C" void kernel_launch(void* const* d_in, const int* in_sizes, int n_in,
                              void* d_out, int out_size, void* d_ws, size_t ws_size,
                              hipStream_t stream) {
  const float* xq = (const float*)d_in[0];
  const float* kv = (const float*)d_in[1];
  const float* wkv = (const float*)d_in[2];
  const float* wq = (const float*)d_in[3];
  const float* wmh = (const float*)d_in[4];
  const float* bmh = (const float*)d_in[5];
  const float* w1 = (const float*)d_in[6];
  const float* b1 = (const float*)d_in[7];
  const float* w2 = (const float*)d_in[8];
  const float* b2 = (const float*)d_in[9];
  const float* g1 = (const float*)d_in[10];
  const float* bb1 = (const float*)d_in[11];
  const float* g2 = (const float*)d_in[12];
  const float* bb2 = (const float*)d_in[13];
  __half* ws = (__half*)d_ws;

  prep_weights<<<(WS_HALVES + 255) / 256, 256, 0, stream>>>(wq, wkv, wmh, w1, w2, ws);

  const int tokens = 32768;
  ca_mfma<<<tokens / TB, 512, 0, stream>>>(xq, kv, ws, bmh, b1, b2,
                                           g1, bb1, g2, bb2, (float*)d_out);
}

// Round 7
// 65.500 us; speedup vs baseline: 1.1535x; 1.1535x over previous
//
#include <hip/hip_runtime.h>
#include <hip/hip_fp16.h>

typedef _Float16 f16x8 __attribute__((ext_vector_type(8)));
typedef float f32x4 __attribute__((ext_vector_type(4)));
typedef unsigned int uint32;

#define LDW 136   // row stride in halves (272B: 16B-aligned)
#define TB  16    // tokens per block

// wait only lgkmcnt(0): vmcnt=63, expcnt=7, lgkmcnt=0 -> 0xC07F
#define WAITLGKM() do { __builtin_amdgcn_s_waitcnt(0xC07F); __builtin_amdgcn_sched_barrier(0); } while(0)

// lgkm-only barrier: drains LDS ops (cross-wave visibility) but leaves global
// loads (VGPR-destined weight/kv/x prefetches) IN FLIGHT across the barrier.
// __syncthreads would emit s_waitcnt vmcnt(0) and kill the prefetch pipeline.
#define BAR() do {                                          \
  asm volatile("s_waitcnt lgkmcnt(0)" ::: "memory");        \
  __builtin_amdgcn_sched_barrier(0);                        \
  __builtin_amdgcn_s_barrier();                             \
  __builtin_amdgcn_sched_barrier(0);                        \
} while (0)

union F16x8U { f16x8 v; __half2 h2[4]; uint2 u2[2]; uint4 u4; };

__device__ __forceinline__ uint32 pk2f(float a, float b) {
  __half2 h = __floats2half2_rn(a, b);
  return *reinterpret_cast<uint32*>(&h);
}
__device__ __forceinline__ float bcast(float v, int sl) {
  return __int_as_float(__builtin_amdgcn_readlane(__float_as_int(v), sl));
}
__device__ __forceinline__ float wred_sum(float v) {
  v += __shfl_xor(v, 32); v += __shfl_xor(v, 16); v += __shfl_xor(v, 8);
  v += __shfl_xor(v, 4);  v += __shfl_xor(v, 2);  v += __shfl_xor(v, 1);
  return v;
}
__device__ __forceinline__ f16x8 ldsv8(const __half* p) {
  return *reinterpret_cast<const f16x8*>(p);   // 16B-aligned -> ds_read_b128
}
__device__ __forceinline__ f32x4 mfma16(f16x8 a, f16x8 b, f32x4 c) {
  return __builtin_amdgcn_mfma_f32_16x16x32_f16(a, b, c, 0, 0, 0);
}
// packed C-frag store: C[m=c_out local][n=tok=fr] -> row-major act[tok][c], 1x ds_write_b64
__device__ __forceinline__ void stp(__half* base, int fr, int fq, int nt, f32x4 a) {
  uint2 u; u.x = pk2f(a[0], a[1]); u.y = pk2f(a[2], a[3]);
  *reinterpret_cast<uint2*>(&base[fr * LDW + nt * 16 + fq * 4]) = u;
}

// ---- workspace layout (halves) ----
#define OFF_WQ   0          // wqT  [c_out 128][c_in 128]
#define OFF_WK2  16384      // wk2  [h 4][i 128][d 40] : wkv[i][h*32+d] (d<32, pad 0)
#define OFF_WV   36864      // wvT  [c_out 128][i 128] : wkv[i][128+c]
#define OFF_WMH  53248      // wmhT
#define OFF_W1   69632      // w1T
#define OFF_W2   86016      // w2T
#define WS_HALVES 102400

__global__ void prep_weights(const float* __restrict__ wq, const float* __restrict__ wkv,
                             const float* __restrict__ wmh, const float* __restrict__ w1,
                             const float* __restrict__ w2, __half* __restrict__ ws) {
  int idx = blockIdx.x * 256 + threadIdx.x;
  if (idx >= WS_HALVES) return;
  float v;
  if (idx < OFF_WK2) {
    int t = idx, c = t >> 7, k = t & 127;
    v = wq[k * 128 + c];
  } else if (idx < OFF_WV) {
    int t = idx - OFF_WK2;
    int d = t % 40, row = t / 40;            // row = h*128 + i
    int h = row >> 7, i = row & 127;
    v = (d < 32) ? wkv[i * 256 + h * 32 + d] : 0.f;
  } else if (idx < OFF_WMH) {
    int t = idx - OFF_WV, c = t >> 7, k = t & 127;
    v = wkv[k * 256 + 128 + c];
  } else if (idx < OFF_W1) {
    int t = idx - OFF_WMH, c = t >> 7, k = t & 127;
    v = wmh[k * 128 + c];
  } else if (idx < OFF_W2) {
    int t = idx - OFF_W1, c = t >> 7, k = t & 127;
    v = w1[k * 128 + c];
  } else {
    int t = idx - OFF_W2, c = t >> 7, k = t & 127;
    v = w2[k * 128 + c];
  }
  ws[idx] = __float2half_rn(v);
}

// load W frags (2 c_out-tiles x 4 k-slices), used as MFMA *A* operand
#define LOADB2(GOFF, NT0, NT1, BF) do {                                          \
  _Pragma("unroll")                                                              \
  for (int t_ = 0; t_ < 2; ++t_) {                                               \
    int nt_ = t_ ? (NT1) : (NT0);                                                \
    _Pragma("unroll")                                                            \
    for (int ks_ = 0; ks_ < 4; ++ks_)                                            \
      BF[t_][ks_] = *reinterpret_cast<const f16x8*>(                             \
          wsv + (GOFF) + (nt_*16 + fr)*128 + ks_*32 + fq*8);                     \
  } } while (0)

// two 16x16 tiles: A = weights (BF), B = activation tile (row-major [tok][c])
#define GEMM2(AT, BF, ACC0, ACC1) do {                                           \
  _Pragma("unroll")                                                              \
  for (int ks_ = 0; ks_ < 4; ++ks_) {                                            \
    f16x8 b_ = ldsv8(&(AT)[fr * LDW + ks_ * 32 + fq * 8]);                       \
    ACC0 = mfma16(BF[0][ks_], b_, ACC0);                                         \
    ACC1 = mfma16(BF[1][ks_], b_, ACC1);                                         \
  } } while (0)

__global__ void __launch_bounds__(256, 6) ca_mfma(
    const float* __restrict__ xq, const float* __restrict__ kvin,
    const __half* __restrict__ wsv,
    const float* __restrict__ bmh, const float* __restrict__ b1,
    const float* __restrict__ b2,
    const float* __restrict__ g1, const float* __restrict__ bb1,
    const float* __restrict__ g2, const float* __restrict__ bb2,
    float* __restrict__ outp)
{
  // LDS: 17408 + 8704 = 26112 B -> 6 blocks/CU
  __shared__ __half QWC[64 * LDW];      // qw/ctx rows [h*16+tok]; then Y/RES/H/V quadrants
  __shared__ __half UBUF[2 * TB * LDW]; // slot0: Xh -> kvw(wv0,1) -> Ob ; slot1: Qb -> kvw(wv2,3)

  const int tid = threadIdx.x;
  const int wv = tid >> 6, lane = tid & 63;
  const int fr = lane & 15, fq = lane >> 4;   // MFMA frag row / k-group
  const int tb = blockIdx.x * TB;
  const int ltb = wv * 4;

  __half* Xh = UBUF;              // slot 0 (dead after P1)
  __half* Qb = UBUF + 2176;       // slot 1 (dead after P2)
  __half* Ob = UBUF;              // slot 0 again (written P4, kvw dead)
  __half* Yb   = QWC;
  __half* RESb = QWC + 16 * LDW;
  __half* Hb   = QWC + 32 * LDW;
  __half* Vb   = QWC + 48 * LDW;

  const f32x4 ZZ = {0.f, 0.f, 0.f, 0.f};

  // ---- entry: prefetch token-0 kv (lane owns 8 consecutive floats) + P1 W frags ----
  float4 pre[4];
  {
    const float4* kv4 = reinterpret_cast<const float4*>(kvin + (size_t)(tb + ltb) * 1024);
    pre[0] = kv4[2 * lane];       pre[1] = kv4[2 * lane + 1];
    pre[2] = kv4[2 * lane + 128]; pre[3] = kv4[2 * lane + 129];
  }
  f16x8 bf[2][4];
  LOADB2(OFF_WQ, wv, 4 + wv, bf);

  // ---- Xh (f16, row-major [tok][c], stride LDW) ----
  {
    int tok = tid >> 4, ko = (tid & 15) * 8;
    const float4* s0 = reinterpret_cast<const float4*>(xq + (size_t)(tb + tok) * 128 + ko);
    float4 a = s0[0], b = s0[1];
    uint4 u; u.x = pk2f(a.x, a.y); u.y = pk2f(a.z, a.w);
    u.z = pk2f(b.x, b.y); u.w = pk2f(b.z, b.w);
    *reinterpret_cast<uint4*>(&Xh[tok * LDW + ko]) = u;
  }
  BAR();  // 1: Xh ready (lgkm); bf(wq)/kv pre stay in flight

  // ---- P1: Q = Wq(A) @ Xh(B) -> Qb[tok][c_out], packed b64 stores ----
  {
    f32x4 aA = ZZ, aB = ZZ;
    GEMM2(Xh, bf, aA, aB);
    stp(Qb, fr, fq, wv, aA);
    stp(Qb, fr, fq, 4 + wv, aB);
  }
  // P2's A = wk2 rows (i), K=32
  f16x8 bq[8];
#pragma unroll
  for (int nt = 0; nt < 8; ++nt)
    bq[nt] = *reinterpret_cast<const f16x8*>(
        wsv + OFF_WK2 + (wv * 128 + nt * 16 + fr) * 40 + fq * 8);
  BAR();  // 2: Qb ready; bq stays in flight; Xh reads done

  // ---- P2: qw[wv][tok][i] = wk2(A) @ q(B) -> QWC[(wv*16+tok)][i], packed stores ----
  {
    f16x8 aq = ldsv8(&Qb[fr * LDW + wv * 32 + fq * 8]);   // B-frag: q[tok=fr][d]
#pragma unroll
    for (int nt = 0; nt < 8; ++nt) {
      f32x4 acc = mfma16(bq[nt], aq, ZZ);
      uint2 u; u.x = pk2f(acc[0], acc[1]); u.y = pk2f(acc[2], acc[3]);
      *reinterpret_cast<uint2*>(&QWC[(wv * 16 + fr) * LDW + nt * 16 + fq * 4]) = u;
    }
  }
  BAR();  // 3: qw ready; Xh/Qb reads done (kvw may overwrite)

  // ---- P3: wave-local attention over this wave's 4 tokens ----
  {
    const int p = lane & 31, hh = p >> 3, kk = p & 7, hf = lane >> 5;
    const int kr = lane >> 4, i8 = (lane & 15) * 8;
    const int l2 = 2 * lane;
    __half* kvw = UBUF + wv * 1088;   // [8][LDW] per wave (aliases Xh/Qb, dead)
#pragma unroll 1
    for (int lt = 0; lt < 4; ++lt) {
      const int ltok = ltb + lt;
      WAITLGKM();   // prior iter's ds_reads of kvw done (WAR)
      {
        uint4 u0, u1;
        u0.x = pk2f(pre[0].x, pre[0].y); u0.y = pk2f(pre[0].z, pre[0].w);
        u0.z = pk2f(pre[1].x, pre[1].y); u0.w = pk2f(pre[1].z, pre[1].w);
        u1.x = pk2f(pre[2].x, pre[2].y); u1.y = pk2f(pre[2].z, pre[2].w);
        u1.z = pk2f(pre[3].x, pre[3].y); u1.w = pk2f(pre[3].z, pre[3].w);
        *reinterpret_cast<uint4*>(&kvw[kr * LDW + i8]) = u0;        // rows 0..3
        *reinterpret_cast<uint4*>(&kvw[(4 + kr) * LDW + i8]) = u1;  // rows 4..7
      }
      if (lt < 3) {   // prefetch next token's kv
        const float4* kv4 = reinterpret_cast<const float4*>(kvin + (size_t)(tb + ltok + 1) * 1024);
        pre[0] = kv4[2 * lane];       pre[1] = kv4[2 * lane + 1];
        pre[2] = kv4[2 * lane + 128]; pre[3] = kv4[2 * lane + 129];
      }
      WAITLGKM();   // kv writes visible within wave
      // sim: lane=(hf,hh,kk); dot over 64 i via 8+8 ds_read_b128
      const __half* qrow = &QWC[(hh * 16 + ltok) * LDW + hf * 64];
      const __half* krow = &kvw[kk * LDW + hf * 64];
      __half2 s0 = __floats2half2_rn(0.f, 0.f), s1 = s0;
#pragma unroll
      for (int e = 0; e < 8; ++e) {
        F16x8U q8, k8;
        q8.v = ldsv8(qrow + e * 8);
        k8.v = ldsv8(krow + e * 8);
        s0 = __hfma2(q8.h2[0], k8.h2[0], s0);
        s1 = __hfma2(q8.h2[1], k8.h2[1], s1);
        s0 = __hfma2(q8.h2[2], k8.h2[2], s0);
        s1 = __hfma2(q8.h2[3], k8.h2[3], s1);
      }
      s0 = __hadd2(s0, s1);
      float acc = (__low2float(s0) + __high2float(s0)) * 0.17677669529663687f;
      acc += __shfl_xor(acc, 32);
      float m = acc;
      m = fmaxf(m, __shfl_xor(m, 1));
      m = fmaxf(m, __shfl_xor(m, 2));
      m = fmaxf(m, __shfl_xor(m, 4));
      float e = __expf(acc - m);
      float sden = e;
      sden += __shfl_xor(sden, 1); sden += __shfl_xor(sden, 2); sden += __shfl_xor(sden, 4);
      float at = __fdividef(e, sden);   // lane p holds attn[h=p>>3][k=p&7]
      // ctx[h][c] = sum_k attn*kv ; lane owns cols 2*lane, 2*lane+1 (b32 LDS ops)
      __half2 kvc[8];
#pragma unroll
      for (int k = 0; k < 8; ++k)
        kvc[k] = *reinterpret_cast<const __half2*>(&kvw[k * LDW + l2]);
#pragma unroll
      for (int h = 0; h < 4; ++h) {
        float c0 = 0.f, c1 = 0.f;
#pragma unroll
        for (int k = 0; k < 8; ++k) {
          float a = bcast(at, h * 8 + k);
          float2 kf = __half22float2(kvc[k]);
          c0 = fmaf(a, kf.x, c0);
          c1 = fmaf(a, kf.y, c1);
        }
        *reinterpret_cast<__half2*>(&QWC[(h * 16 + ltok) * LDW + l2]) =
            __floats2half2_rn(c0, c1);
      }
    }
  }
  LOADB2(OFF_WV, wv, 4 + wv, bf);
  BAR();  // 4: ctx ready; kvw reads done; bf(wv) stays in flight

  // ---- P4: out = WvT(A) @ ctx(B) -> Ob[tok][c], c-tiles (wv, 4+wv), heads h1/h2 ----
  float2 xr[4];   // residual x, issued early for LN1 (lane owns cols 2l,2l+1)
#pragma unroll
  for (int lt = 0; lt < 4; ++lt) {
    int tok = tb + ltb + lt;
    xr[lt] = *reinterpret_cast<const float2*>(&xq[(size_t)tok * 128 + 2 * lane]);
  }
  {
    const int h1 = wv >> 1, h2 = 2 + (wv >> 1);
    f32x4 a1c = ZZ, a2c = ZZ;
#pragma unroll
    for (int ks = 0; ks < 4; ++ks) {
      f16x8 b1f = ldsv8(&QWC[(h1 * 16 + fr) * LDW + ks * 32 + fq * 8]);
      a1c = mfma16(bf[0][ks], b1f, a1c);
      f16x8 b2f = ldsv8(&QWC[(h2 * 16 + fr) * LDW + ks * 32 + fq * 8]);
      a2c = mfma16(bf[1][ks], b2f, a2c);
    }
    stp(Ob, fr, fq, wv, a1c);        // Ob aliases slot 0 (kvw wv0/1 dead)
    stp(Ob, fr, fq, 4 + wv, a2c);
  }
  LOADB2(OFF_WMH, wv, 4 + wv, bf);
  BAR();  // 5: Ob ready; QWC ctx reads done; bf(wmh) stays in flight

  // ---- P5: y = Wmh(A) @ out(B) -> Yb[tok][c] ----
  {
    f32x4 aA = ZZ, aB = ZZ;
    GEMM2(Ob, bf, aA, aB);
    stp(Yb, fr, fq, wv, aA);
    stp(Yb, fr, fq, 4 + wv, aB);
  }
  LOADB2(OFF_W1, wv, 4 + wv, bf);
  BAR();  // 6: Yb ready; bf(w1) stays in flight

  // ---- LN1 + residual -> RESb (lane owns cols 2l,2l+1; b32 LDS, float2 global) ----
  {
    const int l2 = 2 * lane;
    float2 bm = *reinterpret_cast<const float2*>(&bmh[l2]);
    float2 gg = *reinterpret_cast<const float2*>(&g1[l2]);
    float2 cc = *reinterpret_cast<const float2*>(&bb1[l2]);
#pragma unroll
    for (int lt = 0; lt < 4; ++lt) {
      int row = ltb + lt;
      float2 y = __half22float2(*reinterpret_cast<const __half2*>(&Yb[row * LDW + l2]));
      float v0 = y.x + bm.x, v1 = y.y + bm.y;
      float s = wred_sum(v0 + v1);
      float sq = wred_sum(v0 * v0 + v1 * v1);
      float mu = s * 0.0078125f;
      float var = sq * 0.0078125f - mu * mu;
      float rstd = rsqrtf(var + 1e-5f);
      float r0 = (v0 - mu) * rstd * gg.x + cc.x + xr[lt].x;
      float r1 = (v1 - mu) * rstd * gg.y + cc.y + xr[lt].y;
      *reinterpret_cast<__half2*>(&RESb[row * LDW + l2]) = __floats2half2_rn(r0, r1);
    }
  }
  BAR();  // 7: RESb ready

  // ---- P6: h = gelu(W1(A) @ res(B) + b1) -> Hb[tok][c] ----
  {
    f32x4 aA = ZZ, aB = ZZ;
    GEMM2(RESb, bf, aA, aB);
    int c0 = wv * 16 + fq * 4, c1 = 64 + wv * 16 + fq * 4;
    float4 b1a = *reinterpret_cast<const float4*>(&b1[c0]);
    float4 b1b = *reinterpret_cast<const float4*>(&b1[c1]);
    uint2 ua, ub;
    float t0, t1;
    t0 = aA[0] + b1a.x; t0 = 0.5f * t0 * (1.f + erff(t0 * 0.70710678118654752f));
    t1 = aA[1] + b1a.y; t1 = 0.5f * t1 * (1.f + erff(t1 * 0.70710678118654752f));
    ua.x = pk2f(t0, t1);
    t0 = aA[2] + b1a.z; t0 = 0.5f * t0 * (1.f + erff(t0 * 0.70710678118654752f));
    t1 = aA[3] + b1a.w; t1 = 0.5f * t1 * (1.f + erff(t1 * 0.70710678118654752f));
    ua.y = pk2f(t0, t1);
    t0 = aB[0] + b1b.x; t0 = 0.5f * t0 * (1.f + erff(t0 * 0.70710678118654752f));
    t1 = aB[1] + b1b.y; t1 = 0.5f * t1 * (1.f + erff(t1 * 0.70710678118654752f));
    ub.x = pk2f(t0, t1);
    t0 = aB[2] + b1b.z; t0 = 0.5f * t0 * (1.f + erff(t0 * 0.70710678118654752f));
    t1 = aB[3] + b1b.w; t1 = 0.5f * t1 * (1.f + erff(t1 * 0.70710678118654752f));
    ub.y = pk2f(t0, t1);
    *reinterpret_cast<uint2*>(&Hb[fr * LDW + c0]) = ua;
    *reinterpret_cast<uint2*>(&Hb[fr * LDW + c1]) = ub;
  }
  LOADB2(OFF_W2, wv, 4 + wv, bf);
  BAR();  // 8: Hb ready; bf(w2) stays in flight

  // ---- P7: v = W2(A) @ h(B) + b2 + res -> Vb[tok][c] ----
  {
    f32x4 aA = ZZ, aB = ZZ;
    GEMM2(Hb, bf, aA, aB);
    int c0 = wv * 16 + fq * 4, c1 = 64 + wv * 16 + fq * 4;
    float4 b2a = *reinterpret_cast<const float4*>(&b2[c0]);
    float4 b2b = *reinterpret_cast<const float4*>(&b2[c1]);
    F16x8U ra, rb;
    ra.u2[0] = *reinterpret_cast<const uint2*>(&RESb[fr * LDW + c0]);
    rb.u2[0] = *reinterpret_cast<const uint2*>(&RESb[fr * LDW + c1]);
    uint2 ua, ub;
    float2 p0 = __half22float2(ra.h2[0]), p1 = __half22float2(ra.h2[1]);
    ua.x = pk2f(aA[0] + b2a.x + p0.x, aA[1] + b2a.y + p0.y);
    ua.y = pk2f(aA[2] + b2a.z + p1.x, aA[3] + b2a.w + p1.y);
    float2 p2 = __half22float2(rb.h2[0]), p3 = __half22float2(rb.h2[1]);
    ub.x = pk2f(aB[0] + b2b.x + p2.x, aB[1] + b2b.y + p2.y);
    ub.y = pk2f(aB[2] + b2b.z + p3.x, aB[3] + b2b.w + p3.y);
    *reinterpret_cast<uint2*>(&Vb[fr * LDW + c0]) = ua;
    *reinterpret_cast<uint2*>(&Vb[fr * LDW + c1]) = ub;
  }
  BAR();  // 9: Vb ready

  // ---- LN2 + store (lane owns cols 2l,2l+1; float2 out) ----
  {
    const int l2 = 2 * lane;
    float2 gg = *reinterpret_cast<const float2*>(&g2[l2]);
    float2 cc = *reinterpret_cast<const float2*>(&bb2[l2]);
#pragma unroll
    for (int lt = 0; lt < 4; ++lt) {
      int row = ltb + lt, tok = tb + row;
      float2 v = __half22float2(*reinterpret_cast<const __half2*>(&Vb[row * LDW + l2]));
      float s = wred_sum(v.x + v.y);
      float sq = wred_sum(v.x * v.x + v.y * v.y);
      float mu = s * 0.0078125f;
      float var = sq * 0.0078125f - mu * mu;
      float rstd = rsqrtf(var + 1e-5f);
      float2 o;
      o.x = (v.x - mu) * rstd * gg.x + cc.x;
      o.y = (v.y - mu) * rstd * gg.y + cc.y;
      *reinterpret_cast<float2*>(&outp[(size_t)tok * 128 + l2]) = o;
    }
  }
}

extern "C" void kernel_launch(void* const* d_in, const int* in_sizes, int n_in,
                              void* d_out, int out_size, void* d_ws, size_t ws_size,
                              hipStream_t stream) {
  const float* xq = (const float*)d_in[0];
  const float* kv = (const float*)d_in[1];
  const float* wkv = (const float*)d_in[2];
  const float* wq = (const float*)d_in[3];
  const float* wmh = (const float*)d_in[4];
  const float* bmh = (const float*)d_in[5];
  const float* w1 = (const float*)d_in[6];
  const float* b1 = (const float*)d_in[7];
  const float* w2 = (const float*)d_in[8];
  const float* b2 = (const float*)d_in[9];
  const float* g1 = (const float*)d_in[10];
  const float* bb1 = (const float*)d_in[11];
  const float* g2 = (const float*)d_in[12];
  const float* bb2 = (const float*)d_in[13];
  __half* ws = (__half*)d_ws;

  prep_weights<<<(WS_HALVES + 255) / 256, 256, 0, stream>>>(wq, wkv, wmh, w1, w2, ws);

  const int tokens = 32768;
  ca_mfma<<<tokens / TB, 256, 0, stream>>>(xq, kv, ws, bmh, b1, b2,
                                           g1, bb1, g2, bb2, (float*)d_out);
}

// Round 9
// 61.977 us; speedup vs baseline: 1.2191x; 1.0569x over previous
//
#include <hip/hip_runtime.h>
#include <hip/hip_fp16.h>

typedef _Float16 f16x8 __attribute__((ext_vector_type(8)));
typedef float f32x4 __attribute__((ext_vector_type(4)));
typedef unsigned int uint32;

#define LDW 136   // row stride in halves (272B: 16B-aligned)
#define TB  16    // tokens per block

// wait only lgkmcnt(0): vmcnt=63, expcnt=7, lgkmcnt=0 -> 0xC07F
#define WAITLGKM() do { __builtin_amdgcn_s_waitcnt(0xC07F); __builtin_amdgcn_sched_barrier(0); } while(0)

// lgkm-only barrier: leaves global (VGPR-destined) prefetches in flight.
#define BAR() do {                                          \
  asm volatile("s_waitcnt lgkmcnt(0)" ::: "memory");        \
  __builtin_amdgcn_sched_barrier(0);                        \
  __builtin_amdgcn_s_barrier();                             \
  __builtin_amdgcn_sched_barrier(0);                        \
} while (0)

union F16x8U { f16x8 v; __half2 h2[4]; uint2 u2[2]; uint4 u4; };

__device__ __forceinline__ uint32 pk2f(float a, float b) {
  __half2 h = __floats2half2_rn(a, b);
  return *reinterpret_cast<uint32*>(&h);
}
__device__ __forceinline__ float bcast(float v, int sl) {
  return __int_as_float(__builtin_amdgcn_readlane(__float_as_int(v), sl));
}
// DPP move with compile-time control (builtin requires ICE operands)
template <int CTRL, int RMASK = 0xF, int BMASK = 0xF>
__device__ __forceinline__ float dppmov(float v) {
  return __int_as_float(__builtin_amdgcn_update_dpp(
      0, __float_as_int(v), CTRL, RMASK, BMASK, true));
}
template <int PAT>
__device__ __forceinline__ float swzf(float v) {
  return __int_as_float(__builtin_amdgcn_ds_swizzle(__float_as_int(v), PAT));
}
// 64-lane sum via DPP (rocPRIM pattern) -> total broadcast via readlane(63)
__device__ __forceinline__ float wred_sum(float v) {
  v += dppmov<0x111>(v);                      // row_shr:1
  v += dppmov<0x112>(v);                      // row_shr:2
  v += dppmov<0x114>(v);                      // row_shr:4
  v += dppmov<0x118>(v);                      // row_shr:8 -> lanes 15/31/47/63 hold row sums
  v += dppmov<0x142, 0xA>(v);                 // row_bcast:15 (rows 1,3)
  v += dppmov<0x143, 0xC>(v);                 // row_bcast:31 (row 2,3)
  return __int_as_float(__builtin_amdgcn_readlane(__float_as_int(v), 63));
}
__device__ __forceinline__ f16x8 ldsv8(const __half* p) {
  return *reinterpret_cast<const f16x8*>(p);   // 16B-aligned -> ds_read_b128
}
__device__ __forceinline__ f32x4 mfma16(f16x8 a, f16x8 b, f32x4 c) {
  return __builtin_amdgcn_mfma_f32_16x16x32_f16(a, b, c, 0, 0, 0);
}
// packed C-frag store: C[m][n=fr] -> row-major act[tok=fr][c], 1x ds_write_b64
__device__ __forceinline__ void stp(__half* base, int fr, int fq, int nt, f32x4 a) {
  uint2 u; u.x = pk2f(a[0], a[1]); u.y = pk2f(a[2], a[3]);
  *reinterpret_cast<uint2*>(&base[fr * LDW + nt * 16 + fq * 4]) = u;
}

// ---- workspace layout (halves) ----
#define OFF_WQ   0          // wqT  [c_out 128][c_in 128]
#define OFF_WK2  16384      // wk2  [h 4][i 128][d 40] : wkv[i][h*32+d] (d<32, pad 0)
#define OFF_WV   36864      // wvT  [c_out 128][i 128] : wkv[i][128+c]
#define OFF_WMH  53248      // wmhT
#define OFF_W1   69632      // w1T
#define OFF_W2   86016      // w2T
#define WS_HALVES 102400

__global__ void prep_weights(const float* __restrict__ wq, const float* __restrict__ wkv,
                             const float* __restrict__ wmh, const float* __restrict__ w1,
                             const float* __restrict__ w2, __half* __restrict__ ws) {
  int idx = blockIdx.x * 256 + threadIdx.x;
  if (idx >= WS_HALVES) return;
  float v;
  if (idx < OFF_WK2) {
    int t = idx, c = t >> 7, k = t & 127;
    v = wq[k * 128 + c];
  } else if (idx < OFF_WV) {
    int t = idx - OFF_WK2;
    int d = t % 40, row = t / 40;            // row = h*128 + i
    int h = row >> 7, i = row & 127;
    v = (d < 32) ? wkv[i * 256 + h * 32 + d] : 0.f;
  } else if (idx < OFF_WMH) {
    int t = idx - OFF_WV, c = t >> 7, k = t & 127;
    v = wkv[k * 256 + 128 + c];
  } else if (idx < OFF_W1) {
    int t = idx - OFF_WMH, c = t >> 7, k = t & 127;
    v = wmh[k * 128 + c];
  } else if (idx < OFF_W2) {
    int t = idx - OFF_W1, c = t >> 7, k = t & 127;
    v = w1[k * 128 + c];
  } else {
    int t = idx - OFF_W2, c = t >> 7, k = t & 127;
    v = w2[k * 128 + c];
  }
  ws[idx] = __float2half_rn(v);
}

// load W frags (2 c_out-tiles x 4 k-slices), used as MFMA *A* operand
#define LOADB2(GOFF, NT0, NT1, BF) do {                                          \
  _Pragma("unroll")                                                              \
  for (int t_ = 0; t_ < 2; ++t_) {                                               \
    int nt_ = t_ ? (NT1) : (NT0);                                                \
    _Pragma("unroll")                                                            \
    for (int ks_ = 0; ks_ < 4; ++ks_)                                            \
      BF[t_][ks_] = *reinterpret_cast<const f16x8*>(                             \
          wsv + (GOFF) + (nt_*16 + fr)*128 + ks_*32 + fq*8);                     \
  } } while (0)

// two 16x16 tiles: A = weights (BF), B = activation tile (row-major [tok][c])
#define GEMM2(AT, BF, ACC0, ACC1) do {                                           \
  _Pragma("unroll")                                                              \
  for (int ks_ = 0; ks_ < 4; ++ks_) {                                            \
    f16x8 b_ = ldsv8(&(AT)[fr * LDW + ks_ * 32 + fq * 8]);                       \
    ACC0 = mfma16(BF[0][ks_], b_, ACC0);                                         \
    ACC1 = mfma16(BF[1][ks_], b_, ACC1);                                         \
  } } while (0)

__global__ void __launch_bounds__(256, 6) ca_mfma(
    const float* __restrict__ xq, const float* __restrict__ kvin,
    const __half* __restrict__ wsv,
    const float* __restrict__ bmh, const float* __restrict__ b1,
    const float* __restrict__ b2,
    const float* __restrict__ g1, const float* __restrict__ bb1,
    const float* __restrict__ g2, const float* __restrict__ bb2,
    float* __restrict__ outp)
{
  // LDS: 17408 + 8704 = 26112 B -> 6 blocks/CU
  __shared__ __half QWC[64 * LDW];      // qw/ctx rows [h*16+tok]; then Y/RES/H/V quadrants
  __shared__ __half UBUF[2 * TB * LDW]; // slot0: Xh -> kvw(wv0,1) -> Ob ; slot1: Qb -> kvw(wv2,3)

  const int tid = threadIdx.x;
  const int wv = tid >> 6, lane = tid & 63;
  const int fr = lane & 15, fq = lane >> 4;   // MFMA frag row / k-group
  const int tb = blockIdx.x * TB;
  const int ltb = wv * 4;

  __half* Xh = UBUF;              // slot 0 (dead after P1)
  __half* Qb = UBUF + 2176;       // slot 1 (dead after P2)
  __half* Ob = UBUF;              // slot 0 again (written P4, kvw dead)
  __half* Yb   = QWC;
  __half* RESb = QWC + 16 * LDW;
  __half* Hb   = QWC + 32 * LDW;
  __half* Vb   = QWC + 48 * LDW;

  const f32x4 ZZ = {0.f, 0.f, 0.f, 0.f};

  // ---- entry: prefetch token-0 kv (lane owns 8 consecutive floats) + P1 W frags ----
  float4 pre[4];
  {
    const float4* kv4 = reinterpret_cast<const float4*>(kvin + (size_t)(tb + ltb) * 1024);
    pre[0] = kv4[2 * lane];       pre[1] = kv4[2 * lane + 1];
    pre[2] = kv4[2 * lane + 128]; pre[3] = kv4[2 * lane + 129];
  }
  f16x8 bf[2][4];
  LOADB2(OFF_WQ, wv, 4 + wv, bf);

  // ---- Xh (f16, row-major [tok][c], stride LDW) ----
  {
    int tok = tid >> 4, ko = (tid & 15) * 8;
    const float4* s0 = reinterpret_cast<const float4*>(xq + (size_t)(tb + tok) * 128 + ko);
    float4 a = s0[0], b = s0[1];
    uint4 u; u.x = pk2f(a.x, a.y); u.y = pk2f(a.z, a.w);
    u.z = pk2f(b.x, b.y); u.w = pk2f(b.z, b.w);
    *reinterpret_cast<uint4*>(&Xh[tok * LDW + ko]) = u;
  }
  BAR();  // 1: Xh ready; bf(wq)/kv pre stay in flight

  // ---- P1: Q = Wq(A) @ Xh(B) -> Qb[tok][c_out] ----
  {
    f32x4 aA = ZZ, aB = ZZ;
    GEMM2(Xh, bf, aA, aB);
    stp(Qb, fr, fq, wv, aA);
    stp(Qb, fr, fq, 4 + wv, aB);
  }
  // P2's A = wk2 rows (i), K=32
  f16x8 bq[8];
#pragma unroll
  for (int nt = 0; nt < 8; ++nt)
    bq[nt] = *reinterpret_cast<const f16x8*>(
        wsv + OFF_WK2 + (wv * 128 + nt * 16 + fr) * 40 + fq * 8);
  BAR();  // 2: Qb ready; bq stays in flight; Xh reads done

  // ---- P2: qw[wv][tok][i] -> QWC[(wv*16+tok)][i] ----
  {
    f16x8 aq = ldsv8(&Qb[fr * LDW + wv * 32 + fq * 8]);
#pragma unroll
    for (int nt = 0; nt < 8; ++nt) {
      f32x4 acc = mfma16(bq[nt], aq, ZZ);
      uint2 u; u.x = pk2f(acc[0], acc[1]); u.y = pk2f(acc[2], acc[3]);
      *reinterpret_cast<uint2*>(&QWC[(wv * 16 + fr) * LDW + nt * 16 + fq * 4]) = u;
    }
  }
  BAR();  // 3: qw ready; Xh/Qb reads done (kvw may overwrite)

  // ---- P3: wave-local attention, MFMA sim + DPP softmax ----
  {
    const int kr = lane >> 4, i8 = (lane & 15) * 8;
    const int l2 = 2 * lane;
    const float SCALE = 0.17677669529663687f;  // 1/sqrt(32)
    __half* kvw = UBUF + wv * 1088;   // [8][LDW] per wave (aliases Xh/Qb, dead)
#pragma unroll 1
    for (int lt = 0; lt < 4; ++lt) {
      const int ltok = ltb + lt;
      WAITLGKM();   // prior iter's ds_reads of kvw done (WAR)
      {
        uint4 u0, u1;
        u0.x = pk2f(pre[0].x, pre[0].y); u0.y = pk2f(pre[0].z, pre[0].w);
        u0.z = pk2f(pre[1].x, pre[1].y); u0.w = pk2f(pre[1].z, pre[1].w);
        u1.x = pk2f(pre[2].x, pre[2].y); u1.y = pk2f(pre[2].z, pre[2].w);
        u1.z = pk2f(pre[3].x, pre[3].y); u1.w = pk2f(pre[3].z, pre[3].w);
        *reinterpret_cast<uint4*>(&kvw[kr * LDW + i8]) = u0;        // rows 0..3
        *reinterpret_cast<uint4*>(&kvw[(4 + kr) * LDW + i8]) = u1;  // rows 4..7
      }
      if (lt < 3) {   // prefetch next token's kv
        const float4* kv4 = reinterpret_cast<const float4*>(kvin + (size_t)(tb + ltok + 1) * 1024);
        pre[0] = kv4[2 * lane];       pre[1] = kv4[2 * lane + 1];
        pre[2] = kv4[2 * lane + 128]; pre[3] = kv4[2 * lane + 129];
      }
      WAITLGKM();   // kv writes visible within wave
      // sim via MFMA: A = qw rows (h = fr&3), B = kv rows (k = fr&7)
      // D: lane(fr,*) reg r holds sim[h=r][k=fr&7 dup]; valid at fr<8
      f32x4 acc = ZZ;
#pragma unroll
      for (int ks = 0; ks < 4; ++ks) {
        f16x8 a_ = ldsv8(&QWC[((fr & 3) * 16 + ltok) * LDW + ks * 32 + fq * 8]);
        f16x8 b_ = ldsv8(&kvw[(fr & 7) * LDW + ks * 32 + fq * 8]);
        acc = mfma16(a_, b_, acc);
      }
      // softmax over k (8 lanes): xor1/xor2 via quad_perm DPP, xor4 via ds_swizzle
      float at_[4];
#pragma unroll
      for (int r = 0; r < 4; ++r) {
        float s = acc[r] * SCALE;
        float mx = fmaxf(s, dppmov<0xB1>(s));      // quad_perm [1,0,3,2] = xor1
        mx = fmaxf(mx, dppmov<0x4E>(mx));          // quad_perm [2,3,0,1] = xor2
        mx = fmaxf(mx, swzf<0x101F>(mx));          // swizzle xor4
        float e = __expf(s - mx);
        float dn = e + dppmov<0xB1>(e);
        dn += dppmov<0x4E>(dn);
        dn += swzf<0x101F>(dn);
        at_[r] = __fdividef(e, dn);                // lane k (0..7) holds attn[h=r][k]
      }
      // ctx[h][c] = sum_k at*kv ; lane owns cols 2*lane, 2*lane+1
      __half2 kvc[8];
#pragma unroll
      for (int k = 0; k < 8; ++k)
        kvc[k] = *reinterpret_cast<const __half2*>(&kvw[k * LDW + l2]);
#pragma unroll
      for (int h = 0; h < 4; ++h) {
        float c0 = 0.f, c1 = 0.f;
#pragma unroll
        for (int k = 0; k < 8; ++k) {
          float a = bcast(at_[h], k);
          float2 kf = __half22float2(kvc[k]);
          c0 = fmaf(a, kf.x, c0);
          c1 = fmaf(a, kf.y, c1);
        }
        *reinterpret_cast<__half2*>(&QWC[(h * 16 + ltok) * LDW + l2]) =
            __floats2half2_rn(c0, c1);
      }
    }
  }
  LOADB2(OFF_WV, wv, 4 + wv, bf);
  BAR();  // 4: ctx ready; kvw reads done; bf(wv) stays in flight

  // ---- P4: out = WvT(A) @ ctx(B) -> Ob[tok][c] ----
  float2 xr[4];
#pragma unroll
  for (int lt = 0; lt < 4; ++lt) {
    int tok = tb + ltb + lt;
    xr[lt] = *reinterpret_cast<const float2*>(&xq[(size_t)tok * 128 + 2 * lane]);
  }
  {
    const int h1 = wv >> 1, h2 = 2 + (wv >> 1);
    f32x4 a1c = ZZ, a2c = ZZ;
#pragma unroll
    for (int ks = 0; ks < 4; ++ks) {
      f16x8 b1f = ldsv8(&QWC[(h1 * 16 + fr) * LDW + ks * 32 + fq * 8]);
      a1c = mfma16(bf[0][ks], b1f, a1c);
      f16x8 b2f = ldsv8(&QWC[(h2 * 16 + fr) * LDW + ks * 32 + fq * 8]);
      a2c = mfma16(bf[1][ks], b2f, a2c);
    }
    stp(Ob, fr, fq, wv, a1c);
    stp(Ob, fr, fq, 4 + wv, a2c);
  }
  LOADB2(OFF_WMH, wv, 4 + wv, bf);
  BAR();  // 5: Ob ready; QWC ctx reads done; bf(wmh) stays in flight

  // ---- P5: y = Wmh(A) @ out(B) -> Yb[tok][c] ----
  {
    f32x4 aA = ZZ, aB = ZZ;
    GEMM2(Ob, bf, aA, aB);
    stp(Yb, fr, fq, wv, aA);
    stp(Yb, fr, fq, 4 + wv, aB);
  }
  LOADB2(OFF_W1, wv, 4 + wv, bf);
  BAR();  // 6: Yb ready; bf(w1) stays in flight

  // ---- LN1 + residual -> RESb (DPP reductions, no LDS shuffles) ----
  {
    const int l2 = 2 * lane;
    float2 bm = *reinterpret_cast<const float2*>(&bmh[l2]);
    float2 gg = *reinterpret_cast<const float2*>(&g1[l2]);
    float2 cc = *reinterpret_cast<const float2*>(&bb1[l2]);
#pragma unroll
    for (int lt = 0; lt < 4; ++lt) {
      int row = ltb + lt;
      float2 y = __half22float2(*reinterpret_cast<const __half2*>(&Yb[row * LDW + l2]));
      float v0 = y.x + bm.x, v1 = y.y + bm.y;
      float s = wred_sum(v0 + v1);
      float sq = wred_sum(v0 * v0 + v1 * v1);
      float mu = s * 0.0078125f;
      float var = sq * 0.0078125f - mu * mu;
      float rstd = rsqrtf(var + 1e-5f);
      float r0 = (v0 - mu) * rstd * gg.x + cc.x + xr[lt].x;
      float r1 = (v1 - mu) * rstd * gg.y + cc.y + xr[lt].y;
      *reinterpret_cast<__half2*>(&RESb[row * LDW + l2]) = __floats2half2_rn(r0, r1);
    }
  }
  BAR();  // 7: RESb ready

  // ---- P6: h = gelu(W1(A) @ res(B) + b1) -> Hb[tok][c] ----
  {
    f32x4 aA = ZZ, aB = ZZ;
    GEMM2(RESb, bf, aA, aB);
    int c0 = wv * 16 + fq * 4, c1 = 64 + wv * 16 + fq * 4;
    float4 b1a = *reinterpret_cast<const float4*>(&b1[c0]);
    float4 b1b = *reinterpret_cast<const float4*>(&b1[c1]);
    uint2 ua, ub;
    float t0, t1;
    t0 = aA[0] + b1a.x; t0 = 0.5f * t0 * (1.f + erff(t0 * 0.70710678118654752f));
    t1 = aA[1] + b1a.y; t1 = 0.5f * t1 * (1.f + erff(t1 * 0.70710678118654752f));
    ua.x = pk2f(t0, t1);
    t0 = aA[2] + b1a.z; t0 = 0.5f * t0 * (1.f + erff(t0 * 0.70710678118654752f));
    t1 = aA[3] + b1a.w; t1 = 0.5f * t1 * (1.f + erff(t1 * 0.70710678118654752f));
    ua.y = pk2f(t0, t1);
    t0 = aB[0] + b1b.x; t0 = 0.5f * t0 * (1.f + erff(t0 * 0.70710678118654752f));
    t1 = aB[1] + b1b.y; t1 = 0.5f * t1 * (1.f + erff(t1 * 0.70710678118654752f));
    ub.x = pk2f(t0, t1);
    t0 = aB[2] + b1b.z; t0 = 0.5f * t0 * (1.f + erff(t0 * 0.70710678118654752f));
    t1 = aB[3] + b1b.w; t1 = 0.5f * t1 * (1.f + erff(t1 * 0.70710678118654752f));
    ub.y = pk2f(t0, t1);
    *reinterpret_cast<uint2*>(&Hb[fr * LDW + c0]) = ua;
    *reinterpret_cast<uint2*>(&Hb[fr * LDW + c1]) = ub;
  }
  LOADB2(OFF_W2, wv, 4 + wv, bf);
  BAR();  // 8: Hb ready; bf(w2) stays in flight

  // ---- P7: v = W2(A) @ h(B) + b2 + res -> Vb[tok][c] ----
  {
    f32x4 aA = ZZ, aB = ZZ;
    GEMM2(Hb, bf, aA, aB);
    int c0 = wv * 16 + fq * 4, c1 = 64 + wv * 16 + fq * 4;
    float4 b2a = *reinterpret_cast<const float4*>(&b2[c0]);
    float4 b2b = *reinterpret_cast<const float4*>(&b2[c1]);
    F16x8U ra, rb;
    ra.u2[0] = *reinterpret_cast<const uint2*>(&RESb[fr * LDW + c0]);
    rb.u2[0] = *reinterpret_cast<const uint2*>(&RESb[fr * LDW + c1]);
    uint2 ua, ub;
    float2 p0 = __half22float2(ra.h2[0]), p1 = __half22float2(ra.h2[1]);
    ua.x = pk2f(aA[0] + b2a.x + p0.x, aA[1] + b2a.y + p0.y);
    ua.y = pk2f(aA[2] + b2a.z + p1.x, aA[3] + b2a.w + p1.y);
    float2 p2 = __half22float2(rb.h2[0]), p3 = __half22float2(rb.h2[1]);
    ub.x = pk2f(aB[0] + b2b.x + p2.x, aB[1] + b2b.y + p2.y);
    ub.y = pk2f(aB[2] + b2b.z + p3.x, aB[3] + b2b.w + p3.y);
    *reinterpret_cast<uint2*>(&Vb[fr * LDW + c0]) = ua;
    *reinterpret_cast<uint2*>(&Vb[fr * LDW + c1]) = ub;
  }
  BAR();  // 9: Vb ready

  // ---- LN2 + store (DPP reductions) ----
  {
    const int l2 = 2 * lane;
    float2 gg = *reinterpret_cast<const float2*>(&g2[l2]);
    float2 cc = *reinterpret_cast<const float2*>(&bb2[l2]);
#pragma unroll
    for (int lt = 0; lt < 4; ++lt) {
      int row = ltb + lt, tok = tb + row;
      float2 v = __half22float2(*reinterpret_cast<const __half2*>(&Vb[row * LDW + l2]));
      float s = wred_sum(v.x + v.y);
      float sq = wred_sum(v.x * v.x + v.y * v.y);
      float mu = s * 0.0078125f;
      float var = sq * 0.0078125f - mu * mu;
      float rstd = rsqrtf(var + 1e-5f);
      float2 o;
      o.x = (v.x - mu) * rstd * gg.x + cc.x;
      o.y = (v.y - mu) * rstd * gg.y + cc.y;
      *reinterpret_cast<float2*>(&outp[(size_t)tok * 128 + l2]) = o;
    }
  }
}

extern "C" void kernel_launch(void* const* d_in, const int* in_sizes, int n_in,
                              void* d_out, int out_size, void* d_ws, size_t ws_size,
                              hipStream_t stream) {
  const float* xq = (const float*)d_in[0];
  const float* kv = (const float*)d_in[1];
  const float* wkv = (const float*)d_in[2];
  const float* wq = (const float*)d_in[3];
  const float* wmh = (const float*)d_in[4];
  const float* bmh = (const float*)d_in[5];
  const float* w1 = (const float*)d_in[6];
  const float* b1 = (const float*)d_in[7];
  const float* w2 = (const float*)d_in[8];
  const float* b2 = (const float*)d_in[9];
  const float* g1 = (const float*)d_in[10];
  const float* bb1 = (const float*)d_in[11];
  const float* g2 = (const float*)d_in[12];
  const float* bb2 = (const float*)d_in[13];
  __half* ws = (__half*)d_ws;

  prep_weights<<<(WS_HALVES + 255) / 256, 256, 0, stream>>>(wq, wkv, wmh, w1, w2, ws);

  const int tokens = 32768;
  ca_mfma<<<tokens / TB, 256, 0, stream>>>(xq, kv, ws, bmh, b1, b2,
                                           g1, bb1, g2, bb2, (float*)d_out);
}